// Round 9
// baseline (2790.798 us; speedup 1.0000x reference)
//
#include <hip/hip_runtime.h>
#include <hip/hip_bf16.h>
#include <cstdint>
#include <cstddef>

typedef _Float16 half8  __attribute__((ext_vector_type(8)));
typedef float    floatx4 __attribute__((ext_vector_type(4)));
typedef int      int4v   __attribute__((ext_vector_type(4)));

#define S_LEN 200
#define BATCH 2048
#define HID   128
#define T_LEN 50
#define IN_D  44

// Sentinel: two f16 NaNs. h/FC values are finite => data dword never equals it.
#define SENT32 0x7E007E00

// ---- workspace byte offsets ----
#define OFF_ENCW   0ull
#define OFF_DECW   983040ull
#define OFF_RING_E 1978368ull    // [3][8][2048][128] f16 = 12,582,912 B
#define OFF_RING_D 14561280ull   // [3][4][2048][128] f16 = 6,291,456 B (dec uses lane 0 only now)
#define OFF_ORING  20852736ull   // [4][2048][64] f16 = 1,048,576 B
#define OFF_HENC   21901312ull   // [4][2048][128] f16 = 2,097,152 B
#define OFF_CENC   23998464ull   // [4][2048][128] f32 = 4,194,304 B
#define OFF_FLAGS  28192768ull   // int[1024*32]: flag i at [i*32]
// rings contiguous: 19,922,944 B = 4,980,736 dwords

#define SCOPE_AGENT __HIP_MEMORY_SCOPE_AGENT

#define LOG2E  1.44269504f
#define LOG2E2 2.88539008f
__device__ __forceinline__ float sigf(float x){
  float e = __builtin_amdgcn_exp2f(-LOG2E * x);
  return __builtin_amdgcn_rcpf(1.f + e);
}
__device__ __forceinline__ float tanhf_fast(float x){
  float e = __builtin_amdgcn_exp2f(LOG2E2 * x);
  return 1.f - 2.f * __builtin_amdgcn_rcpf(e + 1.f);
}

__device__ __forceinline__ int  ldc(const int* p){ return __hip_atomic_load(p, __ATOMIC_RELAXED, SCOPE_AGENT); }
__device__ __forceinline__ void stc(int* p, int v){ __hip_atomic_store(p, v, __ATOMIC_RELAXED, SCOPE_AGENT); }
__device__ __forceinline__ void drain_vm(){ asm volatile("s_waitcnt vmcnt(0)" ::: "memory"); }
__device__ __forceinline__ int* flagp(int* flags, int idx){ return flags + idx*32; }

// ---- self-contained fabric ops (sc0 sc1 = L1/L2 bypass, MALL-coherent).
// Loads embed their own vmcnt(0): values architecturally valid at asm exit.
__device__ __forceinline__ int4v ld_ring_x4(const int* p){
  int4v r;
  asm volatile("global_load_dwordx4 %0, %1, off sc0 sc1\n\t"
               "s_waitcnt vmcnt(0)"
               : "=v"(r) : "v"(p) : "memory");
  return r;
}
// Fused 2-plane poll (validated round 7): both loads in flight, ONE wait.
__device__ __forceinline__ void ld_ring_x4x2(int4v &r0, int4v &r1,
                                             const int* p0, const int* p1){
  asm volatile("global_load_dwordx4 %0, %2, off sc0 sc1\n\t"
               "global_load_dwordx4 %1, %3, off sc0 sc1\n\t"
               "s_waitcnt vmcnt(0)"
               : "=&v"(r0), "=&v"(r1)
               : "v"(p0), "v"(p1)
               : "memory");
}
__device__ __forceinline__ void st_ring_x4(int* p, int4v v){
  asm volatile("global_store_dwordx4 %0, %1, off sc0 sc1"
               :: "v"(p), "v"(v) : "memory");
}
__device__ __forceinline__ bool any_sent(int4v v){
  return (v.x==SENT32)||(v.y==SENT32)||(v.z==SENT32)||(v.w==SENT32);
}

#define PIN(v) asm volatile("" : "+v"(v))

__global__ void prep_weights(const float* __restrict__ eW0, const float* __restrict__ eWR,
                             const float* __restrict__ eWH, const float* __restrict__ dW0,
                             const float* __restrict__ dWR, const float* __restrict__ dWH,
                             const float* __restrict__ fcW,
                             _Float16* __restrict__ encw, _Float16* __restrict__ decw,
                             int* __restrict__ rings, int* __restrict__ flags)
{
  int i = blockIdx.x*256 + threadIdx.x;
  if (i < 491520) {
    _Float16 v;
    if (i < 32768)      { int j=i>>6, k=i&63; v = (k<IN_D)? (_Float16)eW0[j*IN_D+k] : (_Float16)0.f; }
    else if (i < 229376){ v = (_Float16)eWR[i-32768]; }
    else                { v = (_Float16)eWH[i-229376]; }
    encw[i] = v;
  }
  if (i < 497664) {
    _Float16 v;
    if (i < 32768)      { int j=i>>6, k=i&63; v = (k<IN_D)? (_Float16)dW0[j*IN_D+k] : (_Float16)0.f; }
    else if (i < 229376){ v = (_Float16)dWR[i-32768]; }
    else if (i < 491520){ v = (_Float16)dWH[i-229376]; }
    else { int r=i-491520; int j=r>>7, k=r&127; v = (j<IN_D)? (_Float16)fcW[j*HID+k] : (_Float16)0.f; }
    decw[i] = v;
  }
  for (int j = i; j < 4980736; j += 4096*256) rings[j] = SENT32;  // sentinel-fill all rings
  if (i < 32768) flags[i] = 0;
}

// ============================================================================
// Encoder: round-8 version VERBATIM (passed, ~628 µs). TSTEP=2 + fused
// 2-plane poll + plane-0 publish pipelined under sub-step 1.
// ============================================================================

__global__ __launch_bounds__(512, 2)
void enc_pipe(const float* __restrict__ x, const _Float16* __restrict__ encw,
              const float* __restrict__ enc_b, _Float16* __restrict__ ring,
              _Float16* __restrict__ h_enc, float* __restrict__ c_enc,
              int* __restrict__ flags)
{
  const int tid = threadIdx.x;
  const int w = tid >> 6, lane = tid & 63, quad = lane >> 4, n16 = lane & 15;
  const int l = blockIdx.x >> 6, s = blockIdx.x & 63, r0 = s * 32;
  const int u = w*16 + n16;
  const int KSI = (l == 0) ? 2 : 4;
  const int my4 = tid*4;

  __shared__ _Float16 xb[2][32][136];
  __shared__ _Float16 hA[32][136];
  __shared__ _Float16 hB[32][136];

  for (int i = tid; i < 32*136; i += 512){
    ((_Float16*)xb[0])[i] = (_Float16)0.f;
    ((_Float16*)xb[1])[i] = (_Float16)0.f;
    ((_Float16*)hA)[i] = (_Float16)0.f;
    ((_Float16*)hB)[i] = (_Float16)0.f;
  }

  const _Float16* Wi = (l==0) ? encw : encw + 32768 + (size_t)(l-1)*65536;
  const _Float16* Wh = encw + 229376 + (size_t)l*65536;
  const int KI = KSI * 32;
  floatx4 wfi[4][4], wfh[4][4];
  #pragma unroll
  for (int nt = 0; nt < 4; ++nt){
    const int grow = nt*128 + u;
    #pragma unroll
    for (int ks = 0; ks < 4; ++ks){
      if (ks < KSI){ wfi[nt][ks] = *(const floatx4*)(Wi + (size_t)grow*KI + ks*32 + quad*8); PIN(wfi[nt][ks]); }
      wfh[nt][ks] = *(const floatx4*)(Wh + (size_t)grow*HID + ks*32 + quad*8); PIN(wfh[nt][ks]);
    }
  }
  float breg[4];
  #pragma unroll
  for (int gg = 0; gg < 4; ++gg) breg[gg] = enc_b[l*512 + gg*128 + u];
  float creg[2][4] = {{0.f,0.f,0.f,0.f},{0.f,0.f,0.f,0.f}};

  int xr_r[3], xr_k[3]; bool xr_v[3]; float xr[2][3];
  if (l == 0){
    #pragma unroll
    for (int j = 0; j < 3; ++j){
      int idx = tid + j*512; xr_v[j] = idx < 32*IN_D;
      xr_r[j] = xr_v[j] ? idx / IN_D : 0; xr_k[j] = xr_v[j] ? idx % IN_D : 0;
      #pragma unroll
      for (int p = 0; p < 2; ++p)
        xr[p][j] = xr_v[j] ? x[((size_t)(r0+xr_r[j])*S_LEN + p)*IN_D + xr_k[j]] : 0.f;
    }
  }

  int* cflag_self = flagp(flags, l*64 + s);
  int* cflag_next = flagp(flags, (l+1)*64 + s);
  int seen_cons = 0;

  auto cell = [&](const _Float16 (*xin)[136], const _Float16 (*hin)[136],
                  _Float16 (*hout)[136], bool writeHC){
    #pragma unroll
    for (int m = 0; m < 2; ++m){
      half8 ai[4], ah[4];
      #pragma unroll
      for (int ks = 0; ks < 4; ++ks){
        if (ks < KSI) ai[ks] = *(const half8*)&xin[m*16+n16][ks*32 + quad*8];
        ah[ks] = *(const half8*)&hin[m*16+n16][ks*32 + quad*8];
      }
      floatx4 acc[4];
      #pragma unroll
      for (int nt = 0; nt < 4; ++nt){
        acc[nt] = (floatx4){0.f,0.f,0.f,0.f};
        #pragma unroll
        for (int ks = 0; ks < 4; ++ks){
          if (ks < KSI) acc[nt] = __builtin_amdgcn_mfma_f32_16x16x32_f16(ai[ks], __builtin_bit_cast(half8, wfi[nt][ks]), acc[nt], 0,0,0);
          acc[nt] = __builtin_amdgcn_mfma_f32_16x16x32_f16(ah[ks], __builtin_bit_cast(half8, wfh[nt][ks]), acc[nt], 0,0,0);
        }
      }
      #pragma unroll
      for (int rr = 0; rr < 4; ++rr){
        float ip = acc[0][rr] + breg[0];
        float fp = acc[1][rr] + breg[1];
        float gp = acc[2][rr] + breg[2];
        float op = acc[3][rr] + breg[3];
        float cc = sigf(fp)*creg[m][rr] + sigf(ip)*tanhf_fast(gp);
        float hh = sigf(op)*tanhf_fast(cc);
        creg[m][rr] = cc;
        const int row = m*16 + quad*4 + rr;
        hout[row][u] = (_Float16)hh;
        if (writeHC){
          h_enc[((size_t)l*BATCH + r0 + row)*HID + u] = (_Float16)hh;
          c_enc[((size_t)l*BATCH + r0 + row)*HID + u] = cc;
        }
      }
    }
  };

  __syncthreads();

  const int4v sv = {SENT32, SENT32, SENT32, SENT32};

  for (int q = 0; q < S_LEN/2; ++q){
    if (l == 0){
      #pragma unroll
      for (int p = 0; p < 2; ++p)
        #pragma unroll
        for (int j = 0; j < 3; ++j)
          if (xr_v[j]) xb[p][xr_r[j]][xr_k[j]] = (_Float16)xr[p][j];
    } else {
      const int sbase = (l-1)*8 + ((q&3)<<1);
      int* s0 = (int*)(ring + ((size_t)(sbase+0)*BATCH + r0)*HID) + my4;
      int* s1 = (int*)(ring + ((size_t)(sbase+1)*BATCH + r0)*HID) + my4;
      int4v v0, v1;
      ld_ring_x4x2(v0, v1, s0, s1);
      while (any_sent(v0)){ __builtin_amdgcn_s_sleep(1); v0 = ld_ring_x4(s0); }
      while (any_sent(v1)){ __builtin_amdgcn_s_sleep(1); v1 = ld_ring_x4(s1); }
      *(int4v*)&xb[0][my4>>6][(my4&63)*2] = v0;
      *(int4v*)&xb[1][my4>>6][(my4&63)*2] = v1;
      st_ring_x4(s0, sv);
      st_ring_x4(s1, sv);
    }
    if (tid == 0 && l < 3 && q >= 4){
      while (seen_cons < q-3){
        seen_cons = ldc(cflag_next);
        if (seen_cons < q-3) __builtin_amdgcn_s_sleep(1);
      }
    }
    __syncthreads();

    if (l == 0 && q < S_LEN/2 - 1){
      #pragma unroll
      for (int p = 0; p < 2; ++p)
        #pragma unroll
        for (int j = 0; j < 3; ++j)
          if (xr_v[j]) xr[p][j] = x[((size_t)(r0+xr_r[j])*S_LEN + (2*q+2+p))*IN_D + xr_k[j]];
    }

    cell(xb[0], hA, hB, false);
    __syncthreads();
    if (l < 3){
      const int dbase = l*8 + ((q&3)<<1);
      int* d0p = (int*)(ring + ((size_t)(dbase+0)*BATCH + r0)*HID) + my4;
      st_ring_x4(d0p, *(const int4v*)&hB[my4>>6][(my4&63)*2]);
    }
    cell(xb[1], hB, hA, (q == S_LEN/2 - 1));
    __syncthreads();

    if (l > 0){
      drain_vm();
      if (tid == 0) stc(cflag_self, q+1);
    }
    if (l < 3){
      const int dbase = l*8 + ((q&3)<<1);
      int* d1p = (int*)(ring + ((size_t)(dbase+1)*BATCH + r0)*HID) + my4;
      st_ring_x4(d1p, *(const int4v*)&hA[my4>>6][(my4&63)*2]);
    }
  }
  drain_vm();
}

// ============================================================================
// Decoder, MERGED 2 layers/block: 128 blocks x 1024 thr. Wave-group g=0
// computes layer 2*pair, g=1 computes layer 2*pair+1; the intra-pair handoff
// is an LDS barrier (was a ~6000cy fabric hop). Fabric hops/timestep: 2
// (pair0 h1 -> pair1 via ring_d lane0; pair1 FC -> pair0 via oring), vs 4.
// Flags PROVABLY unnecessary: 1-step feedback loop + depth-4 slots =>
// producer republish is gated (4 steps behind) through its own consume;
// reset visibility guaranteed by each wave's later polls' embedded vmcnt(0)
// plus the uniform drain_vm before Phase D (which also prevents two
// in-flight same-address publishes from non-polling threads).
// __launch_bounds__(1024,4) caps VGPR at 128 so 16 waves fit one CU.
// ============================================================================

__global__ __launch_bounds__(1024, 4)
void dec_pipe(const float* __restrict__ x, const _Float16* __restrict__ decw,
              const float* __restrict__ dec_b, const float* __restrict__ fc_b,
              _Float16* __restrict__ ring, _Float16* __restrict__ oring,
              const _Float16* __restrict__ h_enc, const float* __restrict__ c_enc,
              int* __restrict__ flags, float* __restrict__ out)
{
  (void)flags;
  const int tid  = threadIdx.x;
  const int g    = tid >> 9;          // 0: lower layer of pair, 1: upper
  const int stid = tid & 511;
  const int w = stid >> 6, lane = stid & 63, quad = lane >> 4, n16 = lane & 15;
  const int pair = blockIdx.x >> 6, s = blockIdx.x & 63, r0 = s * 32;
  const int l = pair*2 + g;
  const int u = w*16 + n16;
  const int KSI = (l == 0) ? 2 : 4;
  const int my4 = stid*4;

  __shared__ _Float16 xin[32][136];          // lower-layer input staging
  __shared__ _Float16 hs[2][2][32][136];     // hs[g][t&1]: layer-g h output
  __shared__ _Float16 fcout[32][64];

  for (int i = tid; i < 32*136; i += 1024) ((_Float16*)xin)[i] = (_Float16)0.f;
  for (int i = tid; i < 32*64;  i += 1024) ((_Float16*)fcout)[i] = (_Float16)0.f;

  const _Float16* Wi = (l==0) ? decw : decw + 32768 + (size_t)(l-1)*65536;
  const _Float16* Wh = decw + 229376 + (size_t)l*65536;
  const _Float16* FCW = decw + 491520;
  const int KI = KSI * 32;
  floatx4 wfi[4][4], wfh[4][4];
  #pragma unroll
  for (int nt = 0; nt < 4; ++nt){
    const int grow = nt*128 + u;
    #pragma unroll
    for (int ks = 0; ks < 4; ++ks){
      if (ks < KSI){ wfi[nt][ks] = *(const floatx4*)(Wi + (size_t)grow*KI + ks*32 + quad*8); PIN(wfi[nt][ks]); }
      wfh[nt][ks] = *(const floatx4*)(Wh + (size_t)grow*HID + ks*32 + quad*8); PIN(wfh[nt][ks]);
    }
  }
  float breg[4];
  #pragma unroll
  for (int gg = 0; gg < 4; ++gg) breg[gg] = dec_b[l*512 + gg*128 + u];

  // h(t=-1) = h_enc[l] into hs[g][1] (t=0 reads parity 1)
  {
    int idx = stid*8, rr_ = idx >> 7, kk = idx & 127;
    *(half8*)&hs[g][1][rr_][kk] = *(const half8*)(h_enc + ((size_t)l*BATCH + r0)*HID + rr_*HID + kk);
  }
  float creg[2][4];
  #pragma unroll
  for (int m = 0; m < 2; ++m)
    #pragma unroll
    for (int rr = 0; rr < 4; ++rr)
      creg[m][rr] = c_enc[((size_t)l*BATCH + r0 + m*16 + quad*4 + rr)*HID + u];

  floatx4 wfc[4]; float fcb_j = 0.f;
  const int j = u;
  if (pair == 1 && g == 1 && w < 3){
    #pragma unroll
    for (int ks = 0; ks < 4; ++ks){
      wfc[ks] = *(const floatx4*)(FCW + (size_t)j*HID + ks*32 + quad*8); PIN(wfc[ks]);
    }
    if (j < IN_D) fcb_j = fc_b[j];
  }

  auto cell = [&](const _Float16 (*xinb)[136], const _Float16 (*hin)[136],
                  _Float16 (*hout)[136]){
    #pragma unroll
    for (int m = 0; m < 2; ++m){
      half8 ai[4], ah[4];
      #pragma unroll
      for (int ks = 0; ks < 4; ++ks){
        if (ks < KSI) ai[ks] = *(const half8*)&xinb[m*16+n16][ks*32 + quad*8];
        ah[ks] = *(const half8*)&hin[m*16+n16][ks*32 + quad*8];
      }
      floatx4 acc[4];
      #pragma unroll
      for (int nt = 0; nt < 4; ++nt){
        acc[nt] = (floatx4){0.f,0.f,0.f,0.f};
        #pragma unroll
        for (int ks = 0; ks < 4; ++ks){
          if (ks < KSI) acc[nt] = __builtin_amdgcn_mfma_f32_16x16x32_f16(ai[ks], __builtin_bit_cast(half8, wfi[nt][ks]), acc[nt], 0,0,0);
          acc[nt] = __builtin_amdgcn_mfma_f32_16x16x32_f16(ah[ks], __builtin_bit_cast(half8, wfh[nt][ks]), acc[nt], 0,0,0);
        }
      }
      #pragma unroll
      for (int rr = 0; rr < 4; ++rr){
        float ip = acc[0][rr] + breg[0];
        float fp = acc[1][rr] + breg[1];
        float gp = acc[2][rr] + breg[2];
        float op = acc[3][rr] + breg[3];
        float cc = sigf(fp)*creg[m][rr] + sigf(ip)*tanhf_fast(gp);
        float hh = sigf(op)*tanhf_fast(cc);
        creg[m][rr] = cc;
        hout[m*16 + quad*4 + rr][u] = (_Float16)hh;
      }
    }
  };

  __syncthreads();

  const int4v sv = {SENT32, SENT32, SENT32, SENT32};

  for (int t = 0; t < T_LEN; ++t){
    const int tb = t & 1, pb = tb ^ 1;

    // ---- Phase A: lower-layer input staging (g0 only active) ----
    if (g == 0){
      if (pair == 0){
        if (t == 0){
          for (int idx = stid; idx < 32*IN_D; idx += 512){
            int r = idx / IN_D, k = idx % IN_D;
            xin[r][k] = (_Float16)x[((size_t)(r0+r)*S_LEN + (S_LEN-1))*IN_D + k];
          }
        } else if (stid < 256){
          int* srcd = (int*)(oring + (((size_t)((t-1)&3))*BATCH + r0)*64);
          int4v v = ld_ring_x4(srcd + my4);
          while (any_sent(v)){ __builtin_amdgcn_s_sleep(1); v = ld_ring_x4(srcd + my4); }
          *(int4v*)&xin[my4>>5][(my4&31)*2] = v;
          st_ring_x4(srcd + my4, sv);
        }
      } else {
        int* srcd = (int*)(ring + (((size_t)(t&3))*BATCH + r0)*HID);
        int4v v = ld_ring_x4(srcd + my4);
        while (any_sent(v)){ __builtin_amdgcn_s_sleep(1); v = ld_ring_x4(srcd + my4); }
        *(int4v*)&xin[my4>>6][(my4&63)*2] = v;
        st_ring_x4(srcd + my4, sv);
      }
    }
    __syncthreads();

    // ---- Phase B: lower layer (l0 / l2) ----
    if (g == 0) cell(xin, hs[0][pb], hs[0][tb]);
    __syncthreads();

    // ---- Phase C: upper layer (l1 / l3); input = lower's fresh output ----
    if (g == 1) cell(hs[0][tb], hs[1][pb], hs[1][tb]);
    // Uniform drain: retires this step's slot resets (issued ~2 cells ago)
    // and last step's publishes (prevents same-address store reorder for
    // threads that never poll). Near-free: everything is old.
    drain_vm();
    __syncthreads();

    // ---- Phase D: inter-pair publish / FC ----
    if (pair == 0){
      if (g == 0){
        int* dst = (int*)(ring + (((size_t)(t&3))*BATCH + r0)*HID);
        st_ring_x4(dst + my4, *(const int4v*)&hs[1][tb][my4>>6][(my4&63)*2]);
      }
    } else {
      if (g == 1 && w < 3){
        #pragma unroll
        for (int m = 0; m < 2; ++m){
          half8 a3[4];
          #pragma unroll
          for (int ks = 0; ks < 4; ++ks) a3[ks] = *(const half8*)&hs[1][tb][m*16+n16][ks*32 + quad*8];
          floatx4 facc = (floatx4){0.f,0.f,0.f,0.f};
          #pragma unroll
          for (int ks = 0; ks < 4; ++ks) facc = __builtin_amdgcn_mfma_f32_16x16x32_f16(a3[ks], __builtin_bit_cast(half8, wfc[ks]), facc, 0,0,0);
          #pragma unroll
          for (int rr = 0; rr < 4; ++rr){
            const int row = m*16 + quad*4 + rr;
            float v = facc[rr] + fcb_j;
            fcout[row][j] = (_Float16)v;          // cols 48..63 stay zero
            if (j < IN_D)
              out[((size_t)(r0 + row)*T_LEN + t)*IN_D + j] = v;
          }
        }
      }
    }
    __syncthreads();
    if (pair == 1 && g == 0 && stid < 256){
      int* odst = (int*)(oring + (((size_t)(t&3))*BATCH + r0)*64);
      st_ring_x4(odst + my4, *(const int4v*)&fcout[my4>>5][(my4&31)*2]);
    }
  }
  drain_vm();
}

extern "C" void kernel_launch(void* const* d_in, const int* in_sizes, int n_in,
                              void* d_out, int out_size, void* d_ws, size_t ws_size,
                              hipStream_t stream)
{
  const float* x        = (const float*)d_in[0];
  const float* enc_Wih0 = (const float*)d_in[2];
  const float* enc_WihR = (const float*)d_in[3];
  const float* enc_Whh  = (const float*)d_in[4];
  const float* enc_b    = (const float*)d_in[5];
  const float* dec_Wih0 = (const float*)d_in[6];
  const float* dec_WihR = (const float*)d_in[7];
  const float* dec_Whh  = (const float*)d_in[8];
  const float* dec_b    = (const float*)d_in[9];
  const float* fc_W     = (const float*)d_in[10];
  const float* fc_b     = (const float*)d_in[11];

  char* ws = (char*)d_ws;
  _Float16* encw   = (_Float16*)(ws + OFF_ENCW);
  _Float16* decw   = (_Float16*)(ws + OFF_DECW);
  _Float16* ring_e = (_Float16*)(ws + OFF_RING_E);
  _Float16* ring_d = (_Float16*)(ws + OFF_RING_D);
  _Float16* oring  = (_Float16*)(ws + OFF_ORING);
  _Float16* h_enc  = (_Float16*)(ws + OFF_HENC);
  float*    c_enc  = (float*)(ws + OFF_CENC);
  int*      flags  = (int*)(ws + OFF_FLAGS);
  int*      rings  = (int*)(ws + OFF_RING_E);
  float*    outp   = (float*)d_out;

  prep_weights<<<4096, 256, 0, stream>>>(enc_Wih0, enc_WihR, enc_Whh,
                                         dec_Wih0, dec_WihR, dec_Whh, fc_W,
                                         encw, decw, rings, flags);
  enc_pipe<<<256, 512, 0, stream>>>(x, encw, enc_b, ring_e, h_enc, c_enc, flags);
  dec_pipe<<<128, 1024, 0, stream>>>(x, decw, dec_b, fc_b, ring_d, oring,
                                     h_enc, c_enc, flags, outp);
}

// Round 10
// 2788.946 us; speedup vs baseline: 1.0007x; 1.0007x over previous
//
#include <hip/hip_runtime.h>
#include <hip/hip_bf16.h>
#include <cstdint>
#include <cstddef>

typedef _Float16 half8  __attribute__((ext_vector_type(8)));
typedef float    floatx4 __attribute__((ext_vector_type(4)));
typedef int      int4v   __attribute__((ext_vector_type(4)));

#define S_LEN 200
#define BATCH 2048
#define HID   128
#define T_LEN 50
#define IN_D  44

// Sentinel: two f16 NaNs. h/FC values are finite => data dword never equals it.
#define SENT32 0x7E007E00

// ---- workspace byte offsets ----
#define OFF_ENCW   0ull
#define OFF_DECW   983040ull
#define OFF_RING_E 1978368ull    // [3][8][2048][128] f16 = 12,582,912 B
#define OFF_RING_D 14561280ull   // [3][4][2048][128] f16 = 6,291,456 B (dec uses lane 0 only now)
#define OFF_ORING  20852736ull   // [4][2048][64] f16 = 1,048,576 B
#define OFF_HENC   21901312ull   // [4][2048][128] f16 = 2,097,152 B
#define OFF_CENC   23998464ull   // [4][2048][128] f32 = 4,194,304 B
#define OFF_FLAGS  28192768ull   // int[1024*32]: flag i at [i*32]
// rings contiguous: 19,922,944 B = 4,980,736 dwords

#define SCOPE_AGENT __HIP_MEMORY_SCOPE_AGENT

#define LOG2E  1.44269504f
#define LOG2E2 2.88539008f
__device__ __forceinline__ float sigf(float x){
  float e = __builtin_amdgcn_exp2f(-LOG2E * x);
  return __builtin_amdgcn_rcpf(1.f + e);
}
__device__ __forceinline__ float tanhf_fast(float x){
  float e = __builtin_amdgcn_exp2f(LOG2E2 * x);
  return 1.f - 2.f * __builtin_amdgcn_rcpf(e + 1.f);
}

__device__ __forceinline__ int  ldc(const int* p){ return __hip_atomic_load(p, __ATOMIC_RELAXED, SCOPE_AGENT); }
__device__ __forceinline__ void stc(int* p, int v){ __hip_atomic_store(p, v, __ATOMIC_RELAXED, SCOPE_AGENT); }
__device__ __forceinline__ void drain_vm(){ asm volatile("s_waitcnt vmcnt(0)" ::: "memory"); }
__device__ __forceinline__ int* flagp(int* flags, int idx){ return flags + idx*32; }

// ---- self-contained fabric ops (sc0 sc1 = L1/L2 bypass, MALL-coherent).
// Loads embed their own vmcnt(0): values architecturally valid at asm exit.
__device__ __forceinline__ int4v ld_ring_x4(const int* p){
  int4v r;
  asm volatile("global_load_dwordx4 %0, %1, off sc0 sc1\n\t"
               "s_waitcnt vmcnt(0)"
               : "=v"(r) : "v"(p) : "memory");
  return r;
}
// Fused 2-plane poll (validated round 7): both loads in flight, ONE wait.
__device__ __forceinline__ void ld_ring_x4x2(int4v &r0, int4v &r1,
                                             const int* p0, const int* p1){
  asm volatile("global_load_dwordx4 %0, %2, off sc0 sc1\n\t"
               "global_load_dwordx4 %1, %3, off sc0 sc1\n\t"
               "s_waitcnt vmcnt(0)"
               : "=&v"(r0), "=&v"(r1)
               : "v"(p0), "v"(p1)
               : "memory");
}
__device__ __forceinline__ void st_ring_x4(int* p, int4v v){
  asm volatile("global_store_dwordx4 %0, %1, off sc0 sc1"
               :: "v"(p), "v"(v) : "memory");
}
__device__ __forceinline__ bool any_sent(int4v v){
  return (v.x==SENT32)||(v.y==SENT32)||(v.z==SENT32)||(v.w==SENT32);
}

#define PIN(v) asm volatile("" : "+v"(v))

__global__ void prep_weights(const float* __restrict__ eW0, const float* __restrict__ eWR,
                             const float* __restrict__ eWH, const float* __restrict__ dW0,
                             const float* __restrict__ dWR, const float* __restrict__ dWH,
                             const float* __restrict__ fcW,
                             _Float16* __restrict__ encw, _Float16* __restrict__ decw,
                             int* __restrict__ rings, int* __restrict__ flags)
{
  int i = blockIdx.x*256 + threadIdx.x;
  if (i < 491520) {
    _Float16 v;
    if (i < 32768)      { int j=i>>6, k=i&63; v = (k<IN_D)? (_Float16)eW0[j*IN_D+k] : (_Float16)0.f; }
    else if (i < 229376){ v = (_Float16)eWR[i-32768]; }
    else                { v = (_Float16)eWH[i-229376]; }
    encw[i] = v;
  }
  if (i < 497664) {
    _Float16 v;
    if (i < 32768)      { int j=i>>6, k=i&63; v = (k<IN_D)? (_Float16)dW0[j*IN_D+k] : (_Float16)0.f; }
    else if (i < 229376){ v = (_Float16)dWR[i-32768]; }
    else if (i < 491520){ v = (_Float16)dWH[i-229376]; }
    else { int r=i-491520; int j=r>>7, k=r&127; v = (j<IN_D)? (_Float16)fcW[j*HID+k] : (_Float16)0.f; }
    decw[i] = v;
  }
  for (int j = i; j < 4980736; j += 4096*256) rings[j] = SENT32;  // sentinel-fill all rings
  if (i < 32768) flags[i] = 0;
}

// ============================================================================
// Encoder: round-8 version VERBATIM (passed, ~628 µs). TSTEP=2 + fused
// 2-plane poll + plane-0 publish pipelined under sub-step 1.
// ============================================================================

__global__ __launch_bounds__(512, 2)
void enc_pipe(const float* __restrict__ x, const _Float16* __restrict__ encw,
              const float* __restrict__ enc_b, _Float16* __restrict__ ring,
              _Float16* __restrict__ h_enc, float* __restrict__ c_enc,
              int* __restrict__ flags)
{
  const int tid = threadIdx.x;
  const int w = tid >> 6, lane = tid & 63, quad = lane >> 4, n16 = lane & 15;
  const int l = blockIdx.x >> 6, s = blockIdx.x & 63, r0 = s * 32;
  const int u = w*16 + n16;
  const int KSI = (l == 0) ? 2 : 4;
  const int my4 = tid*4;

  __shared__ _Float16 xb[2][32][136];
  __shared__ _Float16 hA[32][136];
  __shared__ _Float16 hB[32][136];

  for (int i = tid; i < 32*136; i += 512){
    ((_Float16*)xb[0])[i] = (_Float16)0.f;
    ((_Float16*)xb[1])[i] = (_Float16)0.f;
    ((_Float16*)hA)[i] = (_Float16)0.f;
    ((_Float16*)hB)[i] = (_Float16)0.f;
  }

  const _Float16* Wi = (l==0) ? encw : encw + 32768 + (size_t)(l-1)*65536;
  const _Float16* Wh = encw + 229376 + (size_t)l*65536;
  const int KI = KSI * 32;
  floatx4 wfi[4][4], wfh[4][4];
  #pragma unroll
  for (int nt = 0; nt < 4; ++nt){
    const int grow = nt*128 + u;
    #pragma unroll
    for (int ks = 0; ks < 4; ++ks){
      if (ks < KSI){ wfi[nt][ks] = *(const floatx4*)(Wi + (size_t)grow*KI + ks*32 + quad*8); PIN(wfi[nt][ks]); }
      wfh[nt][ks] = *(const floatx4*)(Wh + (size_t)grow*HID + ks*32 + quad*8); PIN(wfh[nt][ks]);
    }
  }
  float breg[4];
  #pragma unroll
  for (int gg = 0; gg < 4; ++gg) breg[gg] = enc_b[l*512 + gg*128 + u];
  float creg[2][4] = {{0.f,0.f,0.f,0.f},{0.f,0.f,0.f,0.f}};

  int xr_r[3], xr_k[3]; bool xr_v[3]; float xr[2][3];
  if (l == 0){
    #pragma unroll
    for (int j = 0; j < 3; ++j){
      int idx = tid + j*512; xr_v[j] = idx < 32*IN_D;
      xr_r[j] = xr_v[j] ? idx / IN_D : 0; xr_k[j] = xr_v[j] ? idx % IN_D : 0;
      #pragma unroll
      for (int p = 0; p < 2; ++p)
        xr[p][j] = xr_v[j] ? x[((size_t)(r0+xr_r[j])*S_LEN + p)*IN_D + xr_k[j]] : 0.f;
    }
  }

  int* cflag_self = flagp(flags, l*64 + s);
  int* cflag_next = flagp(flags, (l+1)*64 + s);
  int seen_cons = 0;

  auto cell = [&](const _Float16 (*xin)[136], const _Float16 (*hin)[136],
                  _Float16 (*hout)[136], bool writeHC){
    #pragma unroll
    for (int m = 0; m < 2; ++m){
      half8 ai[4], ah[4];
      #pragma unroll
      for (int ks = 0; ks < 4; ++ks){
        if (ks < KSI) ai[ks] = *(const half8*)&xin[m*16+n16][ks*32 + quad*8];
        ah[ks] = *(const half8*)&hin[m*16+n16][ks*32 + quad*8];
      }
      floatx4 acc[4];
      #pragma unroll
      for (int nt = 0; nt < 4; ++nt){
        acc[nt] = (floatx4){0.f,0.f,0.f,0.f};
        #pragma unroll
        for (int ks = 0; ks < 4; ++ks){
          if (ks < KSI) acc[nt] = __builtin_amdgcn_mfma_f32_16x16x32_f16(ai[ks], __builtin_bit_cast(half8, wfi[nt][ks]), acc[nt], 0,0,0);
          acc[nt] = __builtin_amdgcn_mfma_f32_16x16x32_f16(ah[ks], __builtin_bit_cast(half8, wfh[nt][ks]), acc[nt], 0,0,0);
        }
      }
      #pragma unroll
      for (int rr = 0; rr < 4; ++rr){
        float ip = acc[0][rr] + breg[0];
        float fp = acc[1][rr] + breg[1];
        float gp = acc[2][rr] + breg[2];
        float op = acc[3][rr] + breg[3];
        float cc = sigf(fp)*creg[m][rr] + sigf(ip)*tanhf_fast(gp);
        float hh = sigf(op)*tanhf_fast(cc);
        creg[m][rr] = cc;
        const int row = m*16 + quad*4 + rr;
        hout[row][u] = (_Float16)hh;
        if (writeHC){
          h_enc[((size_t)l*BATCH + r0 + row)*HID + u] = (_Float16)hh;
          c_enc[((size_t)l*BATCH + r0 + row)*HID + u] = cc;
        }
      }
    }
  };

  __syncthreads();

  const int4v sv = {SENT32, SENT32, SENT32, SENT32};

  for (int q = 0; q < S_LEN/2; ++q){
    if (l == 0){
      #pragma unroll
      for (int p = 0; p < 2; ++p)
        #pragma unroll
        for (int j = 0; j < 3; ++j)
          if (xr_v[j]) xb[p][xr_r[j]][xr_k[j]] = (_Float16)xr[p][j];
    } else {
      const int sbase = (l-1)*8 + ((q&3)<<1);
      int* s0 = (int*)(ring + ((size_t)(sbase+0)*BATCH + r0)*HID) + my4;
      int* s1 = (int*)(ring + ((size_t)(sbase+1)*BATCH + r0)*HID) + my4;
      int4v v0, v1;
      ld_ring_x4x2(v0, v1, s0, s1);
      while (any_sent(v0)){ __builtin_amdgcn_s_sleep(1); v0 = ld_ring_x4(s0); }
      while (any_sent(v1)){ __builtin_amdgcn_s_sleep(1); v1 = ld_ring_x4(s1); }
      *(int4v*)&xb[0][my4>>6][(my4&63)*2] = v0;
      *(int4v*)&xb[1][my4>>6][(my4&63)*2] = v1;
      st_ring_x4(s0, sv);
      st_ring_x4(s1, sv);
    }
    if (tid == 0 && l < 3 && q >= 4){
      while (seen_cons < q-3){
        seen_cons = ldc(cflag_next);
        if (seen_cons < q-3) __builtin_amdgcn_s_sleep(1);
      }
    }
    __syncthreads();

    if (l == 0 && q < S_LEN/2 - 1){
      #pragma unroll
      for (int p = 0; p < 2; ++p)
        #pragma unroll
        for (int j = 0; j < 3; ++j)
          if (xr_v[j]) xr[p][j] = x[((size_t)(r0+xr_r[j])*S_LEN + (2*q+2+p))*IN_D + xr_k[j]];
    }

    cell(xb[0], hA, hB, false);
    __syncthreads();
    if (l < 3){
      const int dbase = l*8 + ((q&3)<<1);
      int* d0p = (int*)(ring + ((size_t)(dbase+0)*BATCH + r0)*HID) + my4;
      st_ring_x4(d0p, *(const int4v*)&hB[my4>>6][(my4&63)*2]);
    }
    cell(xb[1], hB, hA, (q == S_LEN/2 - 1));
    __syncthreads();

    if (l > 0){
      drain_vm();
      if (tid == 0) stc(cflag_self, q+1);
    }
    if (l < 3){
      const int dbase = l*8 + ((q&3)<<1);
      int* d1p = (int*)(ring + ((size_t)(dbase+1)*BATCH + r0)*HID) + my4;
      st_ring_x4(d1p, *(const int4v*)&hA[my4>>6][(my4&63)*2]);
    }
  }
  drain_vm();
}

// ============================================================================
// Decoder, MERGED 2 layers/block (structure PASSED round 9; protocol proven).
// Round-10 fix: __launch_bounds__(1024) with NO min-waves arg. A 1024-thread
// block needs 4 waves/SIMD co-resident => HW-implied VGPR cap 128; the
// explicit ",4" in round 9 made the compiler halve the budget to 64, spilling
// the ~128-VGPR weight set to scratch (FETCH 607 MB, MfmaUtil 1.9%, 3.4x
// slower). Natural usage is ~116 (measured round 8 for the same cell+FC) —
// fits under 128 with no spills.
// ============================================================================

__global__ __launch_bounds__(1024)
void dec_pipe(const float* __restrict__ x, const _Float16* __restrict__ decw,
              const float* __restrict__ dec_b, const float* __restrict__ fc_b,
              _Float16* __restrict__ ring, _Float16* __restrict__ oring,
              const _Float16* __restrict__ h_enc, const float* __restrict__ c_enc,
              int* __restrict__ flags, float* __restrict__ out)
{
  (void)flags;
  const int tid  = threadIdx.x;
  const int g    = tid >> 9;          // 0: lower layer of pair, 1: upper
  const int stid = tid & 511;
  const int w = stid >> 6, lane = stid & 63, quad = lane >> 4, n16 = lane & 15;
  const int pair = blockIdx.x >> 6, s = blockIdx.x & 63, r0 = s * 32;
  const int l = pair*2 + g;
  const int u = w*16 + n16;
  const int KSI = (l == 0) ? 2 : 4;
  const int my4 = stid*4;

  __shared__ _Float16 xin[32][136];          // lower-layer input staging
  __shared__ _Float16 hs[2][2][32][136];     // hs[g][t&1]: layer-g h output
  __shared__ _Float16 fcout[32][64];

  for (int i = tid; i < 32*136; i += 1024) ((_Float16*)xin)[i] = (_Float16)0.f;
  for (int i = tid; i < 32*64;  i += 1024) ((_Float16*)fcout)[i] = (_Float16)0.f;

  const _Float16* Wi = (l==0) ? decw : decw + 32768 + (size_t)(l-1)*65536;
  const _Float16* Wh = decw + 229376 + (size_t)l*65536;
  const _Float16* FCW = decw + 491520;
  const int KI = KSI * 32;
  floatx4 wfi[4][4], wfh[4][4];
  #pragma unroll
  for (int nt = 0; nt < 4; ++nt){
    const int grow = nt*128 + u;
    #pragma unroll
    for (int ks = 0; ks < 4; ++ks){
      if (ks < KSI){ wfi[nt][ks] = *(const floatx4*)(Wi + (size_t)grow*KI + ks*32 + quad*8); PIN(wfi[nt][ks]); }
      wfh[nt][ks] = *(const floatx4*)(Wh + (size_t)grow*HID + ks*32 + quad*8); PIN(wfh[nt][ks]);
    }
  }
  float breg[4];
  #pragma unroll
  for (int gg = 0; gg < 4; ++gg) breg[gg] = dec_b[l*512 + gg*128 + u];

  // h(t=-1) = h_enc[l] into hs[g][1] (t=0 reads parity 1)
  {
    int idx = stid*8, rr_ = idx >> 7, kk = idx & 127;
    *(half8*)&hs[g][1][rr_][kk] = *(const half8*)(h_enc + ((size_t)l*BATCH + r0)*HID + rr_*HID + kk);
  }
  float creg[2][4];
  #pragma unroll
  for (int m = 0; m < 2; ++m)
    #pragma unroll
    for (int rr = 0; rr < 4; ++rr)
      creg[m][rr] = c_enc[((size_t)l*BATCH + r0 + m*16 + quad*4 + rr)*HID + u];

  floatx4 wfc[4]; float fcb_j = 0.f;
  const int j = u;
  if (pair == 1 && g == 1 && w < 3){
    #pragma unroll
    for (int ks = 0; ks < 4; ++ks){
      wfc[ks] = *(const floatx4*)(FCW + (size_t)j*HID + ks*32 + quad*8); PIN(wfc[ks]);
    }
    if (j < IN_D) fcb_j = fc_b[j];
  }

  auto cell = [&](const _Float16 (*xinb)[136], const _Float16 (*hin)[136],
                  _Float16 (*hout)[136]){
    #pragma unroll
    for (int m = 0; m < 2; ++m){
      half8 ai[4], ah[4];
      #pragma unroll
      for (int ks = 0; ks < 4; ++ks){
        if (ks < KSI) ai[ks] = *(const half8*)&xinb[m*16+n16][ks*32 + quad*8];
        ah[ks] = *(const half8*)&hin[m*16+n16][ks*32 + quad*8];
      }
      floatx4 acc[4];
      #pragma unroll
      for (int nt = 0; nt < 4; ++nt){
        acc[nt] = (floatx4){0.f,0.f,0.f,0.f};
        #pragma unroll
        for (int ks = 0; ks < 4; ++ks){
          if (ks < KSI) acc[nt] = __builtin_amdgcn_mfma_f32_16x16x32_f16(ai[ks], __builtin_bit_cast(half8, wfi[nt][ks]), acc[nt], 0,0,0);
          acc[nt] = __builtin_amdgcn_mfma_f32_16x16x32_f16(ah[ks], __builtin_bit_cast(half8, wfh[nt][ks]), acc[nt], 0,0,0);
        }
      }
      #pragma unroll
      for (int rr = 0; rr < 4; ++rr){
        float ip = acc[0][rr] + breg[0];
        float fp = acc[1][rr] + breg[1];
        float gp = acc[2][rr] + breg[2];
        float op = acc[3][rr] + breg[3];
        float cc = sigf(fp)*creg[m][rr] + sigf(ip)*tanhf_fast(gp);
        float hh = sigf(op)*tanhf_fast(cc);
        creg[m][rr] = cc;
        hout[m*16 + quad*4 + rr][u] = (_Float16)hh;
      }
    }
  };

  __syncthreads();

  const int4v sv = {SENT32, SENT32, SENT32, SENT32};

  for (int t = 0; t < T_LEN; ++t){
    const int tb = t & 1, pb = tb ^ 1;

    // ---- Phase A: lower-layer input staging (g0 only active) ----
    if (g == 0){
      if (pair == 0){
        if (t == 0){
          for (int idx = stid; idx < 32*IN_D; idx += 512){
            int r = idx / IN_D, k = idx % IN_D;
            xin[r][k] = (_Float16)x[((size_t)(r0+r)*S_LEN + (S_LEN-1))*IN_D + k];
          }
        } else if (stid < 256){
          int* srcd = (int*)(oring + (((size_t)((t-1)&3))*BATCH + r0)*64);
          int4v v = ld_ring_x4(srcd + my4);
          while (any_sent(v)){ __builtin_amdgcn_s_sleep(1); v = ld_ring_x4(srcd + my4); }
          *(int4v*)&xin[my4>>5][(my4&31)*2] = v;
          st_ring_x4(srcd + my4, sv);
        }
      } else {
        int* srcd = (int*)(ring + (((size_t)(t&3))*BATCH + r0)*HID);
        int4v v = ld_ring_x4(srcd + my4);
        while (any_sent(v)){ __builtin_amdgcn_s_sleep(1); v = ld_ring_x4(srcd + my4); }
        *(int4v*)&xin[my4>>6][(my4&63)*2] = v;
        st_ring_x4(srcd + my4, sv);
      }
    }
    __syncthreads();

    // ---- Phase B: lower layer (l0 / l2) ----
    if (g == 0) cell(xin, hs[0][pb], hs[0][tb]);
    __syncthreads();

    // ---- Phase C: upper layer (l1 / l3); input = lower's fresh output ----
    if (g == 1) cell(hs[0][tb], hs[1][pb], hs[1][tb]);
    // Uniform drain: retires this step's slot resets (issued ~2 cells ago)
    // and last step's publishes (prevents same-address store reorder for
    // threads that never poll). Near-free: everything is old.
    drain_vm();
    __syncthreads();

    // ---- Phase D: inter-pair publish / FC ----
    if (pair == 0){
      if (g == 0){
        int* dst = (int*)(ring + (((size_t)(t&3))*BATCH + r0)*HID);
        st_ring_x4(dst + my4, *(const int4v*)&hs[1][tb][my4>>6][(my4&63)*2]);
      }
    } else {
      if (g == 1 && w < 3){
        #pragma unroll
        for (int m = 0; m < 2; ++m){
          half8 a3[4];
          #pragma unroll
          for (int ks = 0; ks < 4; ++ks) a3[ks] = *(const half8*)&hs[1][tb][m*16+n16][ks*32 + quad*8];
          floatx4 facc = (floatx4){0.f,0.f,0.f,0.f};
          #pragma unroll
          for (int ks = 0; ks < 4; ++ks) facc = __builtin_amdgcn_mfma_f32_16x16x32_f16(a3[ks], __builtin_bit_cast(half8, wfc[ks]), facc, 0,0,0);
          #pragma unroll
          for (int rr = 0; rr < 4; ++rr){
            const int row = m*16 + quad*4 + rr;
            float v = facc[rr] + fcb_j;
            fcout[row][j] = (_Float16)v;          // cols 48..63 stay zero
            if (j < IN_D)
              out[((size_t)(r0 + row)*T_LEN + t)*IN_D + j] = v;
          }
        }
      }
    }
    __syncthreads();
    if (pair == 1 && g == 0 && stid < 256){
      int* odst = (int*)(oring + (((size_t)(t&3))*BATCH + r0)*64);
      st_ring_x4(odst + my4, *(const int4v*)&fcout[my4>>5][(my4&31)*2]);
    }
  }
  drain_vm();
}

extern "C" void kernel_launch(void* const* d_in, const int* in_sizes, int n_in,
                              void* d_out, int out_size, void* d_ws, size_t ws_size,
                              hipStream_t stream)
{
  const float* x        = (const float*)d_in[0];
  const float* enc_Wih0 = (const float*)d_in[2];
  const float* enc_WihR = (const float*)d_in[3];
  const float* enc_Whh  = (const float*)d_in[4];
  const float* enc_b    = (const float*)d_in[5];
  const float* dec_Wih0 = (const float*)d_in[6];
  const float* dec_WihR = (const float*)d_in[7];
  const float* dec_Whh  = (const float*)d_in[8];
  const float* dec_b    = (const float*)d_in[9];
  const float* fc_W     = (const float*)d_in[10];
  const float* fc_b     = (const float*)d_in[11];

  char* ws = (char*)d_ws;
  _Float16* encw   = (_Float16*)(ws + OFF_ENCW);
  _Float16* decw   = (_Float16*)(ws + OFF_DECW);
  _Float16* ring_e = (_Float16*)(ws + OFF_RING_E);
  _Float16* ring_d = (_Float16*)(ws + OFF_RING_D);
  _Float16* oring  = (_Float16*)(ws + OFF_ORING);
  _Float16* h_enc  = (_Float16*)(ws + OFF_HENC);
  float*    c_enc  = (float*)(ws + OFF_CENC);
  int*      flags  = (int*)(ws + OFF_FLAGS);
  int*      rings  = (int*)(ws + OFF_RING_E);
  float*    outp   = (float*)d_out;

  prep_weights<<<4096, 256, 0, stream>>>(enc_Wih0, enc_WihR, enc_Whh,
                                         dec_Wih0, dec_WihR, dec_Whh, fc_W,
                                         encw, decw, rings, flags);
  enc_pipe<<<256, 512, 0, stream>>>(x, encw, enc_b, ring_e, h_enc, c_enc, flags);
  dec_pipe<<<128, 1024, 0, stream>>>(x, decw, dec_b, fc_b, ring_d, oring,
                                     h_enc, c_enc, flags, outp);
}